// Round 1
// baseline (517.873 us; speedup 1.0000x reference)
//
#include <hip/hip_runtime.h>
#include <math.h>

// ---------------------------------------------------------------------------
// DGCNN-style network, B=8, N=2048, K=20, eval-mode BN.
// Pipeline (all fp32, round 0 baseline):
//   knn (fp64 distances, top-20 via packed sortable keys)  -> idx
//   y1 = W1 @ x (pointwise)                                -> y
//   gmax: x1 = lrelu(bn(max_k y1[nbrs]))                   -> Xcat[:,0:64]
//   y2 = W2 @ x1 ... etc (gemm_small)                      -> y
//   gemm5: h = lrelu(bn(W5 @ Xcat)), fused max/sum pooling -> fmax/fsum atomics
//   L1/L2/L3 MLP head                                      -> d_out (8x40)
// Trick: max_k lrelu(bn(h)) == lrelu(bn(max_k h)) when bn scale>=0, min_k when
// scale<0 (both maps monotone). So gather reduces max AND min of pre-BN y.
// ---------------------------------------------------------------------------

#define WS_IDX      0            // int[16384*20]            1,310,720 B
#define WS_Y        1310720      // float[16384*256] max     16,777,216 B
#define WS_XCAT     18087936     // float[16384*512]         33,554,432 B
#define WS_FMAX     51642368     // uint[8*1024]             32,768 B
#define WS_FSUM     51675136     // float[8*1024]            32,768 B
#define WS_A1       51707904     // float[8*512]             16,384 B
#define WS_A2       51724288     // float[8*256]             8,192 B
// total ~49.4 MB

__device__ __forceinline__ unsigned sortable_f32(float f) {
  unsigned b = __float_as_uint(f);
  return (b & 0x80000000u) ? ~b : (b | 0x80000000u);
}
__device__ __forceinline__ float desort_f32(unsigned u) {
  unsigned b = (u & 0x80000000u) ? (u ^ 0x80000000u) : ~u;
  return __uint_as_float(b);
}
__device__ __forceinline__ float lrelu(float v) { return (v >= 0.f) ? v : 0.2f * v; }

// ------------------------------ KNN ----------------------------------------
// One wave per query row. 32 candidates/lane in registers as packed keys:
// key = sortable(negdist_f32) << 32 | (2047 - m). Unique keys -> strictly
// descending extraction needs no exclusion mask; tie at fp32 -> smaller m,
// matching top_k stable tie-break.
__global__ __launch_bounds__(256) void knn_kernel(const float* __restrict__ x,
                                                  int* __restrict__ idxo) {
  int row = blockIdx.x * 4 + (threadIdx.x >> 6);
  int lane = threadIdx.x & 63;
  int b = row >> 11, n = row & 2047;
  const float* xb = x + b * 3 * 2048;
  float q0 = xb[n], q1 = xb[2048 + n], q2 = xb[4096 + n];
  double xxq = (double)q0 * q0 + (double)q1 * q1 + (double)q2 * q2;
  unsigned long long key[32];
#pragma unroll
  for (int j = 0; j < 32; ++j) {
    int m = j * 64 + lane;
    float p0 = xb[m], p1 = xb[2048 + m], p2 = xb[4096 + m];
    double inner = (double)q0 * p0 + (double)q1 * p1 + (double)q2 * p2;
    double xxm = (double)p0 * p0 + (double)p1 * p1 + (double)p2 * p2;
    float nd = (float)(2.0 * inner - xxq - xxm);
    key[j] = ((unsigned long long)sortable_f32(nd) << 32) | (unsigned)(2047 - m);
  }
  unsigned long long prev = ~0ULL;
  for (int t = 0; t < 20; ++t) {
    unsigned long long best = 0;
#pragma unroll
    for (int j = 0; j < 32; ++j) {
      unsigned long long kj = key[j];
      bool ok = (kj < prev) & (kj > best);
      best = ok ? kj : best;
    }
#pragma unroll
    for (int off = 1; off < 64; off <<= 1) {
      unsigned long long o = __shfl_xor(best, off, 64);
      best = (o > best) ? o : best;
    }
    if (lane == 0) idxo[row * 20 + t] = 2047 - (int)(best & 0xFFFFFFFFu);
    prev = best;
  }
}

// ------------------------------ y1 = W1 @ x ---------------------------------
__global__ __launch_bounds__(256) void y1_kernel(const float* __restrict__ x,
                                                 const float* __restrict__ W1,
                                                 float* __restrict__ y) {
  int e = blockIdx.x * 256 + threadIdx.x;  // 16384*64 elements
  int o = e & 63;
  int pg = e >> 6;
  int b = pg >> 11, n = pg & 2047;
  const float* xb = x + b * 6144;
  y[e] = W1[o * 3 + 0] * xb[n] + W1[o * 3 + 1] * xb[2048 + n] +
         W1[o * 3 + 2] * xb[4096 + n];
}

// --------------------- gather max/min + BN + lrelu --------------------------
template <int C, int COFF>
__global__ __launch_bounds__(256) void gmax_kernel(const float* __restrict__ y,
                                                   const int* __restrict__ idx,
                                                   const float* __restrict__ g,
                                                   const float* __restrict__ bb,
                                                   float* __restrict__ xcat) {
  int e = blockIdx.x * 256 + threadIdx.x;  // 16384*C elements
  int c = e & (C - 1);
  int pg = e / C;
  int b = pg >> 11;
  const int* ix = idx + pg * 20;
  int mm[20];
#pragma unroll
  for (int k = 0; k < 20; ++k) mm[k] = ix[k];
  int base = b * 2048 * C + c;
  float mx = -3.4e38f, mn = 3.4e38f;
#pragma unroll
  for (int k = 0; k < 20; ++k) {
    float v = y[base + mm[k] * C];
    mx = fmaxf(mx, v);
    mn = fminf(mn, v);
  }
  float s = g[c] / sqrtf(1.0f + 1e-5f);
  float v = (s >= 0.0f) ? mx : mn;
  v = s * v + bb[c];
  xcat[pg * 512 + COFF + c] = lrelu(v);
}

// --------------------- small GEMM: Y = W @ Xcat-slice -----------------------
// 64x64 tile, 4x4 per thread, KT=16. A[k][o], B[k][p] in LDS (stride 68).
template <int CIN, int COUT, int XOFF>
__global__ __launch_bounds__(256) void gemm_small(const float* __restrict__ W,
                                                  const float* __restrict__ xc,
                                                  float* __restrict__ Y) {
  __shared__ float As[16][68];
  __shared__ float Bs[16][68];
  int tid = threadIdx.x;
  int pg0 = blockIdx.x * 64;
  int o0 = blockIdx.y * 64;
  int tx = tid & 15, ty = tid >> 4;
  int lr = tid >> 2, lc = tid & 3;
  float acc[4][4] = {};
  for (int k0 = 0; k0 < CIN; k0 += 16) {
    float4 av = *(const float4*)&W[(o0 + lr) * CIN + k0 + lc * 4];
    float4 bv = *(const float4*)&xc[(pg0 + lr) * 512 + XOFF + k0 + lc * 4];
    __syncthreads();
    As[lc * 4 + 0][lr] = av.x; As[lc * 4 + 1][lr] = av.y;
    As[lc * 4 + 2][lr] = av.z; As[lc * 4 + 3][lr] = av.w;
    Bs[lc * 4 + 0][lr] = bv.x; Bs[lc * 4 + 1][lr] = bv.y;
    Bs[lc * 4 + 2][lr] = bv.z; Bs[lc * 4 + 3][lr] = bv.w;
    __syncthreads();
#pragma unroll
    for (int k = 0; k < 16; ++k) {
      float4 a = *(const float4*)&As[k][tx * 4];
      float4 b = *(const float4*)&Bs[k][ty * 4];
      float ar[4] = {a.x, a.y, a.z, a.w};
      float br[4] = {b.x, b.y, b.z, b.w};
#pragma unroll
      for (int i = 0; i < 4; ++i)
#pragma unroll
        for (int j = 0; j < 4; ++j) acc[i][j] += ar[i] * br[j];
    }
  }
#pragma unroll
  for (int j = 0; j < 4; ++j) {
    float4 v = {acc[0][j], acc[1][j], acc[2][j], acc[3][j]};
    *(float4*)&Y[(pg0 + ty * 4 + j) * COUT + o0 + tx * 4] = v;
  }
}

// ------------- gemm5: h = lrelu(bn(W5 @ Xcat)) + fused max/sum pool ---------
// 128x128 tile, 8x8 per thread. Epilogue reduces over the 128 points of the
// tile and atomics into f (max via sortable-uint atomicMax, sum via atomicAdd).
__global__ __launch_bounds__(256) void gemm5_kernel(
    const float* __restrict__ W5, const float* __restrict__ xc,
    const float* __restrict__ g5, const float* __restrict__ b5,
    unsigned* __restrict__ fmax, float* __restrict__ fsum) {
  __shared__ float smem[2 * 16 * 132];
  float* As = smem;             // [16][132] A[k][o]
  float* Bs = smem + 16 * 132;  // [16][132] B[k][p]
  int tid = threadIdx.x;
  int pg0 = blockIdx.x * 128;
  int o0 = blockIdx.y * 128;
  int tx = tid & 15, ty = tid >> 4;
  int lr = tid >> 2, lc = tid & 3;
  float acc[8][8] = {};
  for (int k0 = 0; k0 < 512; k0 += 16) {
    float4 a0 = *(const float4*)&W5[(o0 + lr) * 512 + k0 + lc * 4];
    float4 a1 = *(const float4*)&W5[(o0 + lr + 64) * 512 + k0 + lc * 4];
    float4 c0 = *(const float4*)&xc[(pg0 + lr) * 512 + k0 + lc * 4];
    float4 c1 = *(const float4*)&xc[(pg0 + lr + 64) * 512 + k0 + lc * 4];
    __syncthreads();
    As[(lc * 4 + 0) * 132 + lr] = a0.x; As[(lc * 4 + 1) * 132 + lr] = a0.y;
    As[(lc * 4 + 2) * 132 + lr] = a0.z; As[(lc * 4 + 3) * 132 + lr] = a0.w;
    As[(lc * 4 + 0) * 132 + lr + 64] = a1.x; As[(lc * 4 + 1) * 132 + lr + 64] = a1.y;
    As[(lc * 4 + 2) * 132 + lr + 64] = a1.z; As[(lc * 4 + 3) * 132 + lr + 64] = a1.w;
    Bs[(lc * 4 + 0) * 132 + lr] = c0.x; Bs[(lc * 4 + 1) * 132 + lr] = c0.y;
    Bs[(lc * 4 + 2) * 132 + lr] = c0.z; Bs[(lc * 4 + 3) * 132 + lr] = c0.w;
    Bs[(lc * 4 + 0) * 132 + lr + 64] = c1.x; Bs[(lc * 4 + 1) * 132 + lr + 64] = c1.y;
    Bs[(lc * 4 + 2) * 132 + lr + 64] = c1.z; Bs[(lc * 4 + 3) * 132 + lr + 64] = c1.w;
    __syncthreads();
#pragma unroll
    for (int k = 0; k < 16; ++k) {
      float4 av0 = *(const float4*)&As[k * 132 + tx * 8];
      float4 av1 = *(const float4*)&As[k * 132 + tx * 8 + 4];
      float4 bv0 = *(const float4*)&Bs[k * 132 + ty * 8];
      float4 bv1 = *(const float4*)&Bs[k * 132 + ty * 8 + 4];
      float ar[8] = {av0.x, av0.y, av0.z, av0.w, av1.x, av1.y, av1.z, av1.w};
      float br[8] = {bv0.x, bv0.y, bv0.z, bv0.w, bv1.x, bv1.y, bv1.z, bv1.w};
#pragma unroll
      for (int i = 0; i < 8; ++i)
#pragma unroll
        for (int j = 0; j < 8; ++j) acc[i][j] += ar[i] * br[j];
    }
  }
  // epilogue: bn + lrelu + per-thread reduce over its 8 points
  float sc[8], bi[8], mx[8], sm[8];
#pragma unroll
  for (int i = 0; i < 8; ++i) {
    int o = o0 + tx * 8 + i;
    sc[i] = g5[o] / sqrtf(1.0f + 1e-5f);
    bi[i] = b5[o];
    mx[i] = -3.4e38f;
    sm[i] = 0.f;
  }
#pragma unroll
  for (int i = 0; i < 8; ++i)
#pragma unroll
    for (int j = 0; j < 8; ++j) {
      float v = lrelu(acc[i][j] * sc[i] + bi[i]);
      mx[i] = fmaxf(mx[i], v);
      sm[i] += v;
    }
  __syncthreads();
  float* redm = smem;         // [128][16]
  float* reds = smem + 2048;  // [128][16]
#pragma unroll
  for (int i = 0; i < 8; ++i) {
    redm[(tx * 8 + i) * 16 + ty] = mx[i];
    reds[(tx * 8 + i) * 16 + ty] = sm[i];
  }
  __syncthreads();
  if (tid < 128) {
    float m = -3.4e38f, s = 0.f;
#pragma unroll
    for (int t = 0; t < 16; ++t) {
      m = fmaxf(m, redm[tid * 16 + t]);
      s += reds[tid * 16 + t];
    }
    int b = pg0 >> 11;
    atomicMax(&fmax[b * 1024 + o0 + tid], sortable_f32(m));
    atomicAdd(&fsum[b * 1024 + o0 + tid], s);
  }
}

// ------------------------------ MLP head ------------------------------------
__global__ __launch_bounds__(256) void l1_kernel(const unsigned* __restrict__ fmax,
                                                 const float* __restrict__ fsum,
                                                 const float* __restrict__ L1W,
                                                 const float* __restrict__ g6,
                                                 const float* __restrict__ b6,
                                                 float* __restrict__ a1) {
  int gw = (blockIdx.x * 256 + threadIdx.x) >> 6;  // 4096 waves
  int lane = threadIdx.x & 63;
  int b = gw >> 9, o = gw & 511;
  float s = 0.f;
#pragma unroll
  for (int i = 0; i < 32; ++i) {
    int j = lane + i * 64;
    float fj = (j < 1024) ? desort_f32(fmax[b * 1024 + j])
                          : fsum[b * 1024 + j - 1024] * (1.0f / 2048.0f);
    s += fj * L1W[o * 2048 + j];
  }
#pragma unroll
  for (int off = 1; off < 64; off <<= 1) s += __shfl_xor(s, off, 64);
  if (lane == 0) {
    float scv = g6[o] / sqrtf(1.0f + 1e-5f);
    a1[b * 512 + o] = lrelu(s * scv + b6[o]);
  }
}

__global__ __launch_bounds__(256) void l2_kernel(const float* __restrict__ a1,
                                                 const float* __restrict__ L2W,
                                                 const float* __restrict__ L2b,
                                                 const float* __restrict__ g7,
                                                 const float* __restrict__ b7,
                                                 float* __restrict__ a2) {
  int gw = (blockIdx.x * 256 + threadIdx.x) >> 6;  // 2048 waves
  int lane = threadIdx.x & 63;
  int b = gw >> 8, o = gw & 255;
  float s = 0.f;
#pragma unroll
  for (int i = 0; i < 8; ++i) {
    int j = lane + i * 64;
    s += a1[b * 512 + j] * L2W[o * 512 + j];
  }
#pragma unroll
  for (int off = 1; off < 64; off <<= 1) s += __shfl_xor(s, off, 64);
  if (lane == 0) {
    float v = s + L2b[o];
    float scv = g7[o] / sqrtf(1.0f + 1e-5f);
    a2[b * 256 + o] = lrelu(v * scv + b7[o]);
  }
}

__global__ __launch_bounds__(256) void l3_kernel(const float* __restrict__ a2,
                                                 const float* __restrict__ L3W,
                                                 const float* __restrict__ L3b,
                                                 float* __restrict__ out) {
  int gw = (blockIdx.x * 256 + threadIdx.x) >> 6;  // 320 waves
  int lane = threadIdx.x & 63;
  int b = gw / 40, o = gw % 40;
  float s = 0.f;
#pragma unroll
  for (int i = 0; i < 4; ++i) {
    int j = lane + i * 64;
    s += a2[b * 256 + j] * L3W[o * 256 + j];
  }
#pragma unroll
  for (int off = 1; off < 64; off <<= 1) s += __shfl_xor(s, off, 64);
  if (lane == 0) out[b * 40 + o] = s + L3b[o];
}

// ---------------------------------------------------------------------------
extern "C" void kernel_launch(void* const* d_in, const int* in_sizes, int n_in,
                              void* d_out, int out_size, void* d_ws, size_t ws_size,
                              hipStream_t stream) {
  const float* x = (const float*)d_in[0];
  const float* W1 = (const float*)d_in[1];
  const float* W2 = (const float*)d_in[2];
  const float* W3 = (const float*)d_in[3];
  const float* W4 = (const float*)d_in[4];
  const float* W5 = (const float*)d_in[5];
  const float* g1 = (const float*)d_in[6];  const float* b1 = (const float*)d_in[7];
  const float* g2 = (const float*)d_in[8];  const float* b2 = (const float*)d_in[9];
  const float* g3 = (const float*)d_in[10]; const float* b3 = (const float*)d_in[11];
  const float* g4 = (const float*)d_in[12]; const float* b4 = (const float*)d_in[13];
  const float* g5 = (const float*)d_in[14]; const float* b5 = (const float*)d_in[15];
  const float* g6 = (const float*)d_in[16]; const float* b6 = (const float*)d_in[17];
  const float* g7 = (const float*)d_in[18]; const float* b7 = (const float*)d_in[19];
  const float* L1W = (const float*)d_in[20];
  const float* L2W = (const float*)d_in[21];
  const float* L2b = (const float*)d_in[22];
  const float* L3W = (const float*)d_in[23];
  const float* L3b = (const float*)d_in[24];

  char* w = (char*)d_ws;
  int* idxb = (int*)(w + WS_IDX);
  float* y = (float*)(w + WS_Y);
  float* xcat = (float*)(w + WS_XCAT);
  unsigned* fmax = (unsigned*)(w + WS_FMAX);
  float* fsum = (float*)(w + WS_FSUM);
  float* a1 = (float*)(w + WS_A1);
  float* a2 = (float*)(w + WS_A2);

  hipMemsetAsync(w + WS_FMAX, 0, 65536, stream);  // fmax + fsum

  knn_kernel<<<4096, 256, 0, stream>>>(x, idxb);
  y1_kernel<<<4096, 256, 0, stream>>>(x, W1, y);
  gmax_kernel<64, 0><<<4096, 256, 0, stream>>>(y, idxb, g1, b1, xcat);
  gemm_small<64, 64, 0><<<dim3(256, 1), 256, 0, stream>>>(W2, xcat, y);
  gmax_kernel<64, 64><<<4096, 256, 0, stream>>>(y, idxb, g2, b2, xcat);
  gemm_small<64, 128, 64><<<dim3(256, 2), 256, 0, stream>>>(W3, xcat, y);
  gmax_kernel<128, 128><<<8192, 256, 0, stream>>>(y, idxb, g3, b3, xcat);
  gemm_small<128, 256, 128><<<dim3(256, 4), 256, 0, stream>>>(W4, xcat, y);
  gmax_kernel<256, 256><<<16384, 256, 0, stream>>>(y, idxb, g4, b4, xcat);
  gemm5_kernel<<<dim3(128, 8), 256, 0, stream>>>(W5, xcat, g5, b5, fmax, fsum);
  l1_kernel<<<1024, 256, 0, stream>>>(fmax, fsum, L1W, g6, b6, a1);
  l2_kernel<<<512, 256, 0, stream>>>(a1, L2W, L2b, g7, b7, a2);
  l3_kernel<<<80, 256, 0, stream>>>(a2, L3W, L3b, (float*)d_out);
}

// Round 2
// 354.310 us; speedup vs baseline: 1.4616x; 1.4616x over previous
//
#include <hip/hip_runtime.h>
#include <math.h>

// ---------------------------------------------------------------------------
// DGCNN-style network, B=8, N=2048, K=20, eval-mode BN.
// Round 2: gemm5 -> fp16 MFMA (16x16x32_f16), xcat stored fp16, partial-pool
// epilogue (no atomics) + tiny reduce kernel. knn unchanged (profile next).
// Trick (verified r1): max_k lrelu(bn(h)) == lrelu(bn(max_k h)) for bn scale
// >=0, min_k when scale<0 -> gather reduces max AND min of pre-BN y.
// ---------------------------------------------------------------------------

#define WS_IDX      0            // int[16384*20]            1,310,720 B
#define WS_Y        1310720      // float[16384*256] max     16,777,216 B
#define WS_XCAT16   18087936     // half[16384*512]          16,777,216 B
#define WS_W5H      34865152     // half[1024*512]           1,048,576 B
#define WS_PMAX     35913728     // float[128*1024]          524,288 B
#define WS_PSUM     36438016     // float[128*1024]          524,288 B
#define WS_FMAX     36962304     // float[8*1024]            32,768 B
#define WS_FSUM     36995072     // float[8*1024]            32,768 B
#define WS_A1       37027840     // float[8*512]             16,384 B
#define WS_A2       37044224     // float[8*256]             8,192 B
// total ~37.1 MB (fits: r1 used 49.4 MB successfully)

typedef _Float16 f16x8 __attribute__((ext_vector_type(8)));
typedef _Float16 f16x4 __attribute__((ext_vector_type(4)));
typedef float f32x4 __attribute__((ext_vector_type(4)));

__device__ __forceinline__ unsigned sortable_f32(float f) {
  unsigned b = __float_as_uint(f);
  return (b & 0x80000000u) ? ~b : (b | 0x80000000u);
}
__device__ __forceinline__ float lrelu(float v) { return (v >= 0.f) ? v : 0.2f * v; }

// ------------------------------ KNN ----------------------------------------
// One wave per query row. 32 candidates/lane as packed keys:
// key = sortable(negdist_f32) << 32 | (2047 - m). Unique keys -> strictly
// descending extraction; fp32 tie -> smaller m (matches top_k stable order).
__global__ __launch_bounds__(256) void knn_kernel(const float* __restrict__ x,
                                                  int* __restrict__ idxo) {
  int row = blockIdx.x * 4 + (threadIdx.x >> 6);
  int lane = threadIdx.x & 63;
  int b = row >> 11, n = row & 2047;
  const float* xb = x + b * 3 * 2048;
  float q0 = xb[n], q1 = xb[2048 + n], q2 = xb[4096 + n];
  double xxq = (double)q0 * q0 + (double)q1 * q1 + (double)q2 * q2;
  unsigned long long key[32];
#pragma unroll
  for (int j = 0; j < 32; ++j) {
    int m = j * 64 + lane;
    float p0 = xb[m], p1 = xb[2048 + m], p2 = xb[4096 + m];
    double inner = (double)q0 * p0 + (double)q1 * p1 + (double)q2 * p2;
    double xxm = (double)p0 * p0 + (double)p1 * p1 + (double)p2 * p2;
    float nd = (float)(2.0 * inner - xxq - xxm);
    key[j] = ((unsigned long long)sortable_f32(nd) << 32) | (unsigned)(2047 - m);
  }
  unsigned long long prev = ~0ULL;
  for (int t = 0; t < 20; ++t) {
    unsigned long long best = 0;
#pragma unroll
    for (int j = 0; j < 32; ++j) {
      unsigned long long kj = key[j];
      bool ok = (kj < prev) & (kj > best);
      best = ok ? kj : best;
    }
#pragma unroll
    for (int off = 1; off < 64; off <<= 1) {
      unsigned long long o = __shfl_xor(best, off, 64);
      best = (o > best) ? o : best;
    }
    if (lane == 0) idxo[row * 20 + t] = 2047 - (int)(best & 0xFFFFFFFFu);
    prev = best;
  }
}

// ------------------------------ y1 = W1 @ x ---------------------------------
__global__ __launch_bounds__(256) void y1_kernel(const float* __restrict__ x,
                                                 const float* __restrict__ W1,
                                                 float* __restrict__ y) {
  int e = blockIdx.x * 256 + threadIdx.x;  // 16384*64 elements
  int o = e & 63;
  int pg = e >> 6;
  int b = pg >> 11, n = pg & 2047;
  const float* xb = x + b * 6144;
  y[e] = W1[o * 3 + 0] * xb[n] + W1[o * 3 + 1] * xb[2048 + n] +
         W1[o * 3 + 2] * xb[4096 + n];
}

// ----------------------- fp32 -> fp16 weight convert ------------------------
__global__ __launch_bounds__(256) void convert_kernel(const float* __restrict__ in,
                                                      _Float16* __restrict__ out) {
  int i = blockIdx.x * 256 + threadIdx.x;
  out[i] = (_Float16)in[i];
}

// --------------------- gather max/min + BN + lrelu -> fp16 ------------------
template <int C, int COFF>
__global__ __launch_bounds__(256) void gmax_kernel(const float* __restrict__ y,
                                                   const int* __restrict__ idx,
                                                   const float* __restrict__ g,
                                                   const float* __restrict__ bb,
                                                   _Float16* __restrict__ xcat) {
  int e = blockIdx.x * 256 + threadIdx.x;  // 16384*C elements
  int c = e & (C - 1);
  int pg = e / C;
  int b = pg >> 11;
  const int* ix = idx + pg * 20;
  int mm[20];
#pragma unroll
  for (int k = 0; k < 20; ++k) mm[k] = ix[k];
  int base = b * 2048 * C + c;
  float mx = -3.4e38f, mn = 3.4e38f;
#pragma unroll
  for (int k = 0; k < 20; ++k) {
    float v = y[base + mm[k] * C];
    mx = fmaxf(mx, v);
    mn = fminf(mn, v);
  }
  float s = g[c] / sqrtf(1.0f + 1e-5f);
  float v = (s >= 0.0f) ? mx : mn;
  v = s * v + bb[c];
  xcat[pg * 512 + COFF + c] = (_Float16)lrelu(v);
}

// --------------------- small GEMM: Y = W @ Xcat-slice (fp32 VALU) -----------
// 64x64 tile, 4x4 per thread, KT=16. A[k][o], B[k][p] in LDS (stride 68).
// B operand now fp16 (xcat16), converted on LDS store.
template <int CIN, int COUT, int XOFF>
__global__ __launch_bounds__(256) void gemm_small(const float* __restrict__ W,
                                                  const _Float16* __restrict__ xc,
                                                  float* __restrict__ Y) {
  __shared__ float As[16][68];
  __shared__ float Bs[16][68];
  int tid = threadIdx.x;
  int pg0 = blockIdx.x * 64;
  int o0 = blockIdx.y * 64;
  int tx = tid & 15, ty = tid >> 4;
  int lr = tid >> 2, lc = tid & 3;
  float acc[4][4] = {};
  for (int k0 = 0; k0 < CIN; k0 += 16) {
    float4 av = *(const float4*)&W[(o0 + lr) * CIN + k0 + lc * 4];
    f16x4 bh = *(const f16x4*)&xc[(pg0 + lr) * 512 + XOFF + k0 + lc * 4];
    __syncthreads();
    As[lc * 4 + 0][lr] = av.x; As[lc * 4 + 1][lr] = av.y;
    As[lc * 4 + 2][lr] = av.z; As[lc * 4 + 3][lr] = av.w;
    Bs[lc * 4 + 0][lr] = (float)bh[0]; Bs[lc * 4 + 1][lr] = (float)bh[1];
    Bs[lc * 4 + 2][lr] = (float)bh[2]; Bs[lc * 4 + 3][lr] = (float)bh[3];
    __syncthreads();
#pragma unroll
    for (int k = 0; k < 16; ++k) {
      float4 a = *(const float4*)&As[k][tx * 4];
      float4 b = *(const float4*)&Bs[k][ty * 4];
      float ar[4] = {a.x, a.y, a.z, a.w};
      float br[4] = {b.x, b.y, b.z, b.w};
#pragma unroll
      for (int i = 0; i < 4; ++i)
#pragma unroll
        for (int j = 0; j < 4; ++j) acc[i][j] += ar[i] * br[j];
    }
  }
#pragma unroll
  for (int j = 0; j < 4; ++j) {
    float4 v = {acc[0][j], acc[1][j], acc[2][j], acc[3][j]};
    *(float4*)&Y[(pg0 + ty * 4 + j) * COUT + o0 + tx * 4] = v;
  }
}

// ------------- gemm5: h = lrelu(bn(W5h @ xcat16)) via fp16 MFMA -------------
// M=16384 pts, N=1024 ch, K=512. BM=BN=128, BK=32. 4 waves (2x2), each wave
// 64x64 = 4x4 mfma_f32_16x16x32_f16 tiles. Fragment layouts (m89/m120):
//   A: lane holds A[m=lane&15][k=quad*8+j]  B: B[k=quad*8+j][n=lane&15]
//   D: D[row=quad*4+reg][col=lane&15]
// LDS rows padded to 40 halfs (80 B) -> 2-way bank aliasing only (free).
// Epilogue: bn+lrelu, reduce max/sum over the 128 points, write per-block
// partials (no atomics); reduce5_kernel folds 16 m-blocks per batch.
__global__ __launch_bounds__(256) void gemm5_kernel(
    const _Float16* __restrict__ Wh, const _Float16* __restrict__ Xc,
    const float* __restrict__ g5, const float* __restrict__ b5,
    float* __restrict__ pmax, float* __restrict__ psum) {
  __shared__ _Float16 Xs[128 * 40];
  __shared__ _Float16 Ws[128 * 40];
  __shared__ float pm[256], ps[256];
  int tid = threadIdx.x;
  int lane = tid & 63, w = tid >> 6;
  int wm = w & 1, wn = w >> 1;
  int col = lane & 15, quad = lane >> 4;
  int pg0 = blockIdx.x * 128;
  int o0 = blockIdx.y * 128;
  int r0 = tid >> 2;         // 0..63
  int c8 = (tid & 3) * 8;    // 0,8,16,24

  f32x4 acc[4][4] = {};
  for (int k0 = 0; k0 < 512; k0 += 32) {
    f16x8 xa = *(const f16x8*)&Xc[(pg0 + r0) * 512 + k0 + c8];
    f16x8 xb = *(const f16x8*)&Xc[(pg0 + r0 + 64) * 512 + k0 + c8];
    f16x8 wa = *(const f16x8*)&Wh[(o0 + r0) * 512 + k0 + c8];
    f16x8 wb = *(const f16x8*)&Wh[(o0 + r0 + 64) * 512 + k0 + c8];
    __syncthreads();
    *(f16x8*)&Xs[r0 * 40 + c8] = xa;
    *(f16x8*)&Xs[(r0 + 64) * 40 + c8] = xb;
    *(f16x8*)&Ws[r0 * 40 + c8] = wa;
    *(f16x8*)&Ws[(r0 + 64) * 40 + c8] = wb;
    __syncthreads();
    f16x8 af[4], bf[4];
#pragma unroll
    for (int t = 0; t < 4; ++t) {
      af[t] = *(const f16x8*)&Xs[(wm * 64 + t * 16 + col) * 40 + quad * 8];
      bf[t] = *(const f16x8*)&Ws[(wn * 64 + t * 16 + col) * 40 + quad * 8];
    }
#pragma unroll
    for (int mt = 0; mt < 4; ++mt)
#pragma unroll
      for (int nt = 0; nt < 4; ++nt)
        acc[mt][nt] = __builtin_amdgcn_mfma_f32_16x16x32_f16(af[mt], bf[nt],
                                                             acc[mt][nt], 0, 0, 0);
  }
  // epilogue: bn + lrelu, per-lane reduce over its 16 point-values per channel
  float inv = 1.0f / sqrtf(1.0f + 1e-5f);
#pragma unroll
  for (int nt = 0; nt < 4; ++nt) {
    int o = o0 + wn * 64 + nt * 16 + col;
    float sc = g5[o] * inv, bi = b5[o];
    float mx = -3.4e38f, sm = 0.f;
#pragma unroll
    for (int mt = 0; mt < 4; ++mt)
#pragma unroll
      for (int r = 0; r < 4; ++r) {
        float v = lrelu(acc[mt][nt][r] * sc + bi);
        mx = fmaxf(mx, v);
        sm += v;
      }
    // fold the 4 quads (same col, different points)
    mx = fmaxf(mx, __shfl_xor(mx, 16, 64));
    sm += __shfl_xor(sm, 16, 64);
    mx = fmaxf(mx, __shfl_xor(mx, 32, 64));
    sm += __shfl_xor(sm, 32, 64);
    if (quad == 0) {
      pm[wm * 128 + wn * 64 + nt * 16 + col] = mx;
      ps[wm * 128 + wn * 64 + nt * 16 + col] = sm;
    }
  }
  __syncthreads();
  if (tid < 128) {
    float m = fmaxf(pm[tid], pm[128 + tid]);
    float s = ps[tid] + ps[128 + tid];
    pmax[blockIdx.x * 1024 + o0 + tid] = m;
    psum[blockIdx.x * 1024 + o0 + tid] = s;
  }
}

// fold 16 m-block partials per (batch, channel)
__global__ __launch_bounds__(256) void reduce5_kernel(const float* __restrict__ pmax,
                                                      const float* __restrict__ psum,
                                                      float* __restrict__ fmax,
                                                      float* __restrict__ fsum) {
  int t = blockIdx.x * 256 + threadIdx.x;  // 8192
  int b = t >> 10, o = t & 1023;
  float m = -3.4e38f, s = 0.f;
#pragma unroll
  for (int i = 0; i < 16; ++i) {
    m = fmaxf(m, pmax[(b * 16 + i) * 1024 + o]);
    s += psum[(b * 16 + i) * 1024 + o];
  }
  fmax[t] = m;
  fsum[t] = s;
}

// ------------------------------ MLP head ------------------------------------
__global__ __launch_bounds__(256) void l1_kernel(const float* __restrict__ fmax,
                                                 const float* __restrict__ fsum,
                                                 const float* __restrict__ L1W,
                                                 const float* __restrict__ g6,
                                                 const float* __restrict__ b6,
                                                 float* __restrict__ a1) {
  int gw = (blockIdx.x * 256 + threadIdx.x) >> 6;  // 4096 waves
  int lane = threadIdx.x & 63;
  int b = gw >> 9, o = gw & 511;
  float s = 0.f;
#pragma unroll
  for (int i = 0; i < 32; ++i) {
    int j = lane + i * 64;
    float fj = (j < 1024) ? fmax[b * 1024 + j]
                          : fsum[b * 1024 + j - 1024] * (1.0f / 2048.0f);
    s += fj * L1W[o * 2048 + j];
  }
#pragma unroll
  for (int off = 1; off < 64; off <<= 1) s += __shfl_xor(s, off, 64);
  if (lane == 0) {
    float scv = g6[o] / sqrtf(1.0f + 1e-5f);
    a1[b * 512 + o] = lrelu(s * scv + b6[o]);
  }
}

__global__ __launch_bounds__(256) void l2_kernel(const float* __restrict__ a1,
                                                 const float* __restrict__ L2W,
                                                 const float* __restrict__ L2b,
                                                 const float* __restrict__ g7,
                                                 const float* __restrict__ b7,
                                                 float* __restrict__ a2) {
  int gw = (blockIdx.x * 256 + threadIdx.x) >> 6;  // 2048 waves
  int lane = threadIdx.x & 63;
  int b = gw >> 8, o = gw & 255;
  float s = 0.f;
#pragma unroll
  for (int i = 0; i < 8; ++i) {
    int j = lane + i * 64;
    s += a1[b * 512 + j] * L2W[o * 512 + j];
  }
#pragma unroll
  for (int off = 1; off < 64; off <<= 1) s += __shfl_xor(s, off, 64);
  if (lane == 0) {
    float v = s + L2b[o];
    float scv = g7[o] / sqrtf(1.0f + 1e-5f);
    a2[b * 256 + o] = lrelu(v * scv + b7[o]);
  }
}

__global__ __launch_bounds__(256) void l3_kernel(const float* __restrict__ a2,
                                                 const float* __restrict__ L3W,
                                                 const float* __restrict__ L3b,
                                                 float* __restrict__ out) {
  int gw = (blockIdx.x * 256 + threadIdx.x) >> 6;  // 320 waves
  int lane = threadIdx.x & 63;
  int b = gw / 40, o = gw % 40;
  float s = 0.f;
#pragma unroll
  for (int i = 0; i < 4; ++i) {
    int j = lane + i * 64;
    s += a2[b * 256 + j] * L3W[o * 256 + j];
  }
#pragma unroll
  for (int off = 1; off < 64; off <<= 1) s += __shfl_xor(s, off, 64);
  if (lane == 0) out[b * 40 + o] = s + L3b[o];
}

// ---------------------------------------------------------------------------
extern "C" void kernel_launch(void* const* d_in, const int* in_sizes, int n_in,
                              void* d_out, int out_size, void* d_ws, size_t ws_size,
                              hipStream_t stream) {
  const float* x = (const float*)d_in[0];
  const float* W1 = (const float*)d_in[1];
  const float* W2 = (const float*)d_in[2];
  const float* W3 = (const float*)d_in[3];
  const float* W4 = (const float*)d_in[4];
  const float* W5 = (const float*)d_in[5];
  const float* g1 = (const float*)d_in[6];  const float* b1 = (const float*)d_in[7];
  const float* g2 = (const float*)d_in[8];  const float* b2 = (const float*)d_in[9];
  const float* g3 = (const float*)d_in[10]; const float* b3 = (const float*)d_in[11];
  const float* g4 = (const float*)d_in[12]; const float* b4 = (const float*)d_in[13];
  const float* g5 = (const float*)d_in[14]; const float* b5 = (const float*)d_in[15];
  const float* g6 = (const float*)d_in[16]; const float* b6 = (const float*)d_in[17];
  const float* g7 = (const float*)d_in[18]; const float* b7 = (const float*)d_in[19];
  const float* L1W = (const float*)d_in[20];
  const float* L2W = (const float*)d_in[21];
  const float* L2b = (const float*)d_in[22];
  const float* L3W = (const float*)d_in[23];
  const float* L3b = (const float*)d_in[24];

  char* w = (char*)d_ws;
  int* idxb = (int*)(w + WS_IDX);
  float* y = (float*)(w + WS_Y);
  _Float16* xcat16 = (_Float16*)(w + WS_XCAT16);
  _Float16* w5h = (_Float16*)(w + WS_W5H);
  float* pmax = (float*)(w + WS_PMAX);
  float* psum = (float*)(w + WS_PSUM);
  float* fmax = (float*)(w + WS_FMAX);
  float* fsum = (float*)(w + WS_FSUM);
  float* a1 = (float*)(w + WS_A1);
  float* a2 = (float*)(w + WS_A2);

  convert_kernel<<<2048, 256, 0, stream>>>(W5, w5h);  // 1024*512
  knn_kernel<<<4096, 256, 0, stream>>>(x, idxb);
  y1_kernel<<<4096, 256, 0, stream>>>(x, W1, y);
  gmax_kernel<64, 0><<<4096, 256, 0, stream>>>(y, idxb, g1, b1, xcat16);
  gemm_small<64, 64, 0><<<dim3(256, 1), 256, 0, stream>>>(W2, xcat16, y);
  gmax_kernel<64, 64><<<4096, 256, 0, stream>>>(y, idxb, g2, b2, xcat16);
  gemm_small<64, 128, 64><<<dim3(256, 2), 256, 0, stream>>>(W3, xcat16, y);
  gmax_kernel<128, 128><<<8192, 256, 0, stream>>>(y, idxb, g3, b3, xcat16);
  gemm_small<128, 256, 128><<<dim3(256, 4), 256, 0, stream>>>(W4, xcat16, y);
  gmax_kernel<256, 256><<<16384, 256, 0, stream>>>(y, idxb, g4, b4, xcat16);
  gemm5_kernel<<<dim3(128, 8), 256, 0, stream>>>(w5h, xcat16, g5, b5, pmax, psum);
  reduce5_kernel<<<32, 256, 0, stream>>>(pmax, psum, fmax, fsum);
  l1_kernel<<<1024, 256, 0, stream>>>(fmax, fsum, L1W, g6, b6, a1);
  l2_kernel<<<512, 256, 0, stream>>>(a1, L2W, L2b, g7, b7, a2);
  l3_kernel<<<80, 256, 0, stream>>>(a2, L3W, L3b, (float*)d_out);
}

// Round 3
// 303.028 us; speedup vs baseline: 1.7090x; 1.1692x over previous
//
#include <hip/hip_runtime.h>
#include <math.h>

// ---------------------------------------------------------------------------
// DGCNN-style network, B=8, N=2048, K=20, eval-mode BN.
// Round 3: knn -> 32-iter value-bisection top-k (set semantics, exact index
// tie-break); all GEMMs fp16 MFMA; y stored fp16 (halves gather traffic).
// Trick (verified r1/r2): max_k lrelu(bn(h)) == lrelu(bn(max_k h)) for bn
// scale>=0, min_k when scale<0 -> gather reduces max AND min of pre-BN y.
// ---------------------------------------------------------------------------

#define WS_IDX      0            // int[16384*20]            1,310,720 B
#define WS_XX       1310720      // float[16384]             65,536 B
#define WS_Y16      1376256      // half[16384*256]          8,388,608 B
#define WS_XCAT16   9764864      // half[16384*512]          16,777,216 B
#define WS_W16      26542080     // half[569344]             1,138,688 B
#define WS_PMAX     27680768     // float[128*1024]          524,288 B
#define WS_PSUM     28205056     // float[128*1024]          524,288 B
#define WS_FMAX     28729344     // float[8*1024]            32,768 B
#define WS_FSUM     28762112     // float[8*1024]            32,768 B
#define WS_A1       28794880     // float[8*512]             16,384 B
#define WS_A2       28811264     // float[8*256]             8,192 B
// total ~28.8 MB

typedef _Float16 f16x8 __attribute__((ext_vector_type(8)));
typedef float f32x4 __attribute__((ext_vector_type(4)));

__device__ __forceinline__ float lrelu(float v) { return (v >= 0.f) ? v : 0.2f * v; }

// -------- prep: convert W2..W5 -> fp16 block + per-point sum-of-squares -----
// w16 layout (elements): W2@0 (4096), W3@4096 (8192), W4@12288 (32768),
// W5@45056 (524288). Tail threads compute xx[16384].
__global__ __launch_bounds__(256) void prep_kernel(
    const float* __restrict__ W2, const float* __restrict__ W3,
    const float* __restrict__ W4, const float* __restrict__ W5,
    const float* __restrict__ x, _Float16* __restrict__ w16,
    float* __restrict__ xx) {
  int i = blockIdx.x * 256 + threadIdx.x;
  if (i < 4096) w16[i] = (_Float16)W2[i];
  else if (i < 12288) w16[i] = (_Float16)W3[i - 4096];
  else if (i < 45056) w16[i] = (_Float16)W4[i - 12288];
  else if (i < 569344) w16[i] = (_Float16)W5[i - 45056];
  else if (i < 585728) {
    int p = i - 569344;
    int b = p >> 11, n = p & 2047;
    const float* xb = x + b * 6144;
    float a0 = xb[n], a1 = xb[2048 + n], a2 = xb[4096 + n];
    xx[p] = a0 * a0 + a1 * a1 + a2 * a2;
  }
}

// ------------------------------ KNN ----------------------------------------
// One wave per query row; 32 candidates/lane as sortable-u32 keys of fp32
// neg-distance. Bisection (32 iters) finds K20 = 20th-largest key value;
// emit all keys > K20 (ballot prefix), then 20-cg boundary ties by ascending
// index m (matches jax.lax.top_k stable tie-break; output ORDER is free since
// idx only feeds max/min reduces).
__global__ __launch_bounds__(256) void knn_kernel(const float* __restrict__ x,
                                                  const float* __restrict__ xx,
                                                  int* __restrict__ idxo) {
  int row = blockIdx.x * 4 + (threadIdx.x >> 6);
  int lane = threadIdx.x & 63;
  int b = row >> 11, n = row & 2047;
  const float* xb = x + b * 6144;
  const float* xxb = xx + b * 2048;
  float q0 = xb[n], q1 = xb[2048 + n], q2 = xb[4096 + n];
  float xxq = xxb[n];
  unsigned key[32];
#pragma unroll
  for (int j = 0; j < 32; ++j) {
    int m = j * 64 + lane;
    float inner = q0 * xb[m] + q1 * xb[2048 + m] + q2 * xb[4096 + m];
    float nd = 2.0f * inner - xxq - xxb[m];
    unsigned bb = __float_as_uint(nd);
    key[j] = (bb & 0x80000000u) ? ~bb : (bb | 0x80000000u);
  }
  // bisection: lo converges to max{v : count(key >= v) >= 20}
  unsigned lo = 0u, hi = 0xFFFFFFFFu;
  for (int it = 0; it < 32; ++it) {
    unsigned mid = (unsigned)(((unsigned long long)lo + hi + 1ull) >> 1);
    int cnt = 0;
#pragma unroll
    for (int j = 0; j < 32; ++j)
      cnt += __popcll(__ballot(key[j] >= mid));
    if (cnt >= 20) lo = mid; else hi = mid - 1;
  }
  unsigned K20 = lo;
  // emit strictly-greater candidates, positions via ballot prefix
  unsigned long long ltmask = (1ull << lane) - 1ull;
  int outb = row * 20;
  int base = 0;
#pragma unroll
  for (int j = 0; j < 32; ++j) {
    unsigned long long msk = __ballot(key[j] > K20);
    if (key[j] > K20) idxo[outb + base + __popcll(msk & ltmask)] = j * 64 + lane;
    base += __popcll(msk);
  }
  // boundary ties: take (20 - base) smallest m among key == K20
  int t = 20 - base;
  int lastm = -1;
  for (int r = 0; r < t; ++r) {
    int jbest = 32;
#pragma unroll
    for (int j = 31; j >= 0; --j) {
      int m = j * 64 + lane;
      jbest = (key[j] == K20 && m > lastm) ? j : jbest;
    }
    int mbest = (jbest < 32) ? jbest * 64 + lane : 0x7FFFFFFF;
#pragma unroll
    for (int off = 1; off < 64; off <<= 1) {
      int o = __shfl_xor(mbest, off, 64);
      mbest = (o < mbest) ? o : mbest;
    }
    if (lane == 0) idxo[outb + base + r] = mbest;
    lastm = mbest;
  }
}

// ------------------------------ y1 = W1 @ x ---------------------------------
__global__ __launch_bounds__(256) void y1_kernel(const float* __restrict__ x,
                                                 const float* __restrict__ W1,
                                                 _Float16* __restrict__ y) {
  int e = blockIdx.x * 256 + threadIdx.x;  // 16384*64 elements
  int o = e & 63;
  int pg = e >> 6;
  int b = pg >> 11, n = pg & 2047;
  const float* xb = x + b * 6144;
  y[e] = (_Float16)(W1[o * 3 + 0] * xb[n] + W1[o * 3 + 1] * xb[2048 + n] +
                    W1[o * 3 + 2] * xb[4096 + n]);
}

// --------------------- gather max/min + BN + lrelu -> fp16 ------------------
template <int C, int COFF>
__global__ __launch_bounds__(256) void gmax_kernel(const _Float16* __restrict__ y,
                                                   const int* __restrict__ idx,
                                                   const float* __restrict__ g,
                                                   const float* __restrict__ bb,
                                                   _Float16* __restrict__ xcat) {
  int e = blockIdx.x * 256 + threadIdx.x;  // 16384*C elements
  int c = e & (C - 1);
  int pg = e / C;
  int b = pg >> 11;
  const int* ix = idx + pg * 20;
  int mm[20];
#pragma unroll
  for (int k = 0; k < 20; ++k) mm[k] = ix[k];
  int base = b * 2048 * C + c;
  float mx = -3.4e38f, mn = 3.4e38f;
#pragma unroll
  for (int k = 0; k < 20; ++k) {
    float v = (float)y[base + mm[k] * C];
    mx = fmaxf(mx, v);
    mn = fminf(mn, v);
  }
  float s = g[c] / sqrtf(1.0f + 1e-5f);
  float v = (s >= 0.0f) ? mx : mn;
  v = s * v + bb[c];
  xcat[pg * 512 + COFF + c] = (_Float16)lrelu(v);
}

// ------------- fp16 MFMA GEMM: Y16 = Wh @ xcat-slice ------------------------
// BM=128, BN=min(COUT,128), BK=32. 4 waves: BN==128 -> 2x2 (64x64/wave),
// BN==64 -> 4x1 (32x64/wave). Fragment scheme identical to gemm5 (verified).
template <int CIN, int COUT, int XOFF>
__global__ __launch_bounds__(256) void gemm_mfma(const _Float16* __restrict__ Wh,
                                                 const _Float16* __restrict__ Xc,
                                                 _Float16* __restrict__ Y) {
  constexpr int BN = (COUT < 128) ? COUT : 128;
  constexpr int MT = (BN == 128) ? 4 : 2;
  __shared__ _Float16 Xs[128 * 40];
  __shared__ _Float16 Ws[BN * 40];
  int tid = threadIdx.x;
  int lane = tid & 63, w = tid >> 6;
  int wm = (BN == 128) ? (w & 1) : w;
  int wn = (BN == 128) ? (w >> 1) : 0;
  int col = lane & 15, quad = lane >> 4;
  int pg0 = blockIdx.x * 128;
  int o0 = blockIdx.y * BN;
  int r0 = tid >> 2;
  int c8 = (tid & 3) * 8;
  f32x4 acc[MT][4] = {};
  for (int k0 = 0; k0 < CIN; k0 += 32) {
    f16x8 xa = *(const f16x8*)&Xc[(pg0 + r0) * 512 + XOFF + k0 + c8];
    f16x8 xb2 = *(const f16x8*)&Xc[(pg0 + r0 + 64) * 512 + XOFF + k0 + c8];
    f16x8 wa = *(const f16x8*)&Wh[(o0 + r0) * CIN + k0 + c8];
    f16x8 wb;
    if (BN == 128) wb = *(const f16x8*)&Wh[(o0 + r0 + 64) * CIN + k0 + c8];
    __syncthreads();
    *(f16x8*)&Xs[r0 * 40 + c8] = xa;
    *(f16x8*)&Xs[(r0 + 64) * 40 + c8] = xb2;
    *(f16x8*)&Ws[r0 * 40 + c8] = wa;
    if (BN == 128) *(f16x8*)&Ws[(r0 + 64) * 40 + c8] = wb;
    __syncthreads();
    f16x8 af[MT], bf[4];
#pragma unroll
    for (int t = 0; t < MT; ++t)
      af[t] = *(const f16x8*)&Xs[(wm * (MT * 16) + t * 16 + col) * 40 + quad * 8];
#pragma unroll
    for (int t = 0; t < 4; ++t)
      bf[t] = *(const f16x8*)&Ws[(wn * 64 + t * 16 + col) * 40 + quad * 8];
#pragma unroll
    for (int mt = 0; mt < MT; ++mt)
#pragma unroll
      for (int nt = 0; nt < 4; ++nt)
        acc[mt][nt] = __builtin_amdgcn_mfma_f32_16x16x32_f16(af[mt], bf[nt],
                                                             acc[mt][nt], 0, 0, 0);
  }
#pragma unroll
  for (int mt = 0; mt < MT; ++mt)
#pragma unroll
    for (int nt = 0; nt < 4; ++nt)
#pragma unroll
      for (int r = 0; r < 4; ++r) {
        int p = pg0 + wm * (MT * 16) + mt * 16 + quad * 4 + r;
        int ch = o0 + wn * 64 + nt * 16 + col;
        Y[p * COUT + ch] = (_Float16)acc[mt][nt][r];
      }
}

// ------------- gemm5: h = lrelu(bn(W5h @ xcat16)) via fp16 MFMA -------------
__global__ __launch_bounds__(256) void gemm5_kernel(
    const _Float16* __restrict__ Wh, const _Float16* __restrict__ Xc,
    const float* __restrict__ g5, const float* __restrict__ b5,
    float* __restrict__ pmax, float* __restrict__ psum) {
  __shared__ _Float16 Xs[128 * 40];
  __shared__ _Float16 Ws[128 * 40];
  __shared__ float pm[256], ps[256];
  int tid = threadIdx.x;
  int lane = tid & 63, w = tid >> 6;
  int wm = w & 1, wn = w >> 1;
  int col = lane & 15, quad = lane >> 4;
  int pg0 = blockIdx.x * 128;
  int o0 = blockIdx.y * 128;
  int r0 = tid >> 2;
  int c8 = (tid & 3) * 8;

  f32x4 acc[4][4] = {};
  for (int k0 = 0; k0 < 512; k0 += 32) {
    f16x8 xa = *(const f16x8*)&Xc[(pg0 + r0) * 512 + k0 + c8];
    f16x8 xb = *(const f16x8*)&Xc[(pg0 + r0 + 64) * 512 + k0 + c8];
    f16x8 wa = *(const f16x8*)&Wh[(o0 + r0) * 512 + k0 + c8];
    f16x8 wb = *(const f16x8*)&Wh[(o0 + r0 + 64) * 512 + k0 + c8];
    __syncthreads();
    *(f16x8*)&Xs[r0 * 40 + c8] = xa;
    *(f16x8*)&Xs[(r0 + 64) * 40 + c8] = xb;
    *(f16x8*)&Ws[r0 * 40 + c8] = wa;
    *(f16x8*)&Ws[(r0 + 64) * 40 + c8] = wb;
    __syncthreads();
    f16x8 af[4], bf[4];
#pragma unroll
    for (int t = 0; t < 4; ++t) {
      af[t] = *(const f16x8*)&Xs[(wm * 64 + t * 16 + col) * 40 + quad * 8];
      bf[t] = *(const f16x8*)&Ws[(wn * 64 + t * 16 + col) * 40 + quad * 8];
    }
#pragma unroll
    for (int mt = 0; mt < 4; ++mt)
#pragma unroll
      for (int nt = 0; nt < 4; ++nt)
        acc[mt][nt] = __builtin_amdgcn_mfma_f32_16x16x32_f16(af[mt], bf[nt],
                                                             acc[mt][nt], 0, 0, 0);
  }
  float inv = 1.0f / sqrtf(1.0f + 1e-5f);
#pragma unroll
  for (int nt = 0; nt < 4; ++nt) {
    int o = o0 + wn * 64 + nt * 16 + col;
    float sc = g5[o] * inv, bi = b5[o];
    float mx = -3.4e38f, sm = 0.f;
#pragma unroll
    for (int mt = 0; mt < 4; ++mt)
#pragma unroll
      for (int r = 0; r < 4; ++r) {
        float v = lrelu(acc[mt][nt][r] * sc + bi);
        mx = fmaxf(mx, v);
        sm += v;
      }
    mx = fmaxf(mx, __shfl_xor(mx, 16, 64));
    sm += __shfl_xor(sm, 16, 64);
    mx = fmaxf(mx, __shfl_xor(mx, 32, 64));
    sm += __shfl_xor(sm, 32, 64);
    if (quad == 0) {
      pm[wm * 128 + wn * 64 + nt * 16 + col] = mx;
      ps[wm * 128 + wn * 64 + nt * 16 + col] = sm;
    }
  }
  __syncthreads();
  if (tid < 128) {
    float m = fmaxf(pm[tid], pm[128 + tid]);
    float s = ps[tid] + ps[128 + tid];
    pmax[blockIdx.x * 1024 + o0 + tid] = m;
    psum[blockIdx.x * 1024 + o0 + tid] = s;
  }
}

// fold 16 m-block partials per (batch, channel)
__global__ __launch_bounds__(256) void reduce5_kernel(const float* __restrict__ pmax,
                                                      const float* __restrict__ psum,
                                                      float* __restrict__ fmax,
                                                      float* __restrict__ fsum) {
  int t = blockIdx.x * 256 + threadIdx.x;  // 8192
  int b = t >> 10, o = t & 1023;
  float m = -3.4e38f, s = 0.f;
#pragma unroll
  for (int i = 0; i < 16; ++i) {
    m = fmaxf(m, pmax[(b * 16 + i) * 1024 + o]);
    s += psum[(b * 16 + i) * 1024 + o];
  }
  fmax[t] = m;
  fsum[t] = s;
}

// ------------------------------ MLP head ------------------------------------
__global__ __launch_bounds__(256) void l1_kernel(const float* __restrict__ fmax,
                                                 const float* __restrict__ fsum,
                                                 const float* __restrict__ L1W,
                                                 const float* __restrict__ g6,
                                                 const float* __restrict__ b6,
                                                 float* __restrict__ a1) {
  int gw = (blockIdx.x * 256 + threadIdx.x) >> 6;  // 4096 waves
  int lane = threadIdx.x & 63;
  int b = gw >> 9, o = gw & 511;
  float s = 0.f;
#pragma unroll
  for (int i = 0; i < 32; ++i) {
    int j = lane + i * 64;
    float fj = (j < 1024) ? fmax[b * 1024 + j]
                          : fsum[b * 1024 + j - 1024] * (1.0f / 2048.0f);
    s += fj * L1W[o * 2048 + j];
  }
#pragma unroll
  for (int off = 1; off < 64; off <<= 1) s += __shfl_xor(s, off, 64);
  if (lane == 0) {
    float scv = g6[o] / sqrtf(1.0f + 1e-5f);
    a1[b * 512 + o] = lrelu(s * scv + b6[o]);
  }
}

__global__ __launch_bounds__(256) void l2_kernel(const float* __restrict__ a1,
                                                 const float* __restrict__ L2W,
                                                 const float* __restrict__ L2b,
                                                 const float* __restrict__ g7,
                                                 const float* __restrict__ b7,
                                                 float* __restrict__ a2) {
  int gw = (blockIdx.x * 256 + threadIdx.x) >> 6;  // 2048 waves
  int lane = threadIdx.x & 63;
  int b = gw >> 8, o = gw & 255;
  float s = 0.f;
#pragma unroll
  for (int i = 0; i < 8; ++i) {
    int j = lane + i * 64;
    s += a1[b * 512 + j] * L2W[o * 512 + j];
  }
#pragma unroll
  for (int off = 1; off < 64; off <<= 1) s += __shfl_xor(s, off, 64);
  if (lane == 0) {
    float v = s + L2b[o];
    float scv = g7[o] / sqrtf(1.0f + 1e-5f);
    a2[b * 256 + o] = lrelu(v * scv + b7[o]);
  }
}

__global__ __launch_bounds__(256) void l3_kernel(const float* __restrict__ a2,
                                                 const float* __restrict__ L3W,
                                                 const float* __restrict__ L3b,
                                                 float* __restrict__ out) {
  int gw = (blockIdx.x * 256 + threadIdx.x) >> 6;  // 320 waves
  int lane = threadIdx.x & 63;
  int b = gw / 40, o = gw % 40;
  float s = 0.f;
#pragma unroll
  for (int i = 0; i < 4; ++i) {
    int j = lane + i * 64;
    s += a2[b * 256 + j] * L3W[o * 256 + j];
  }
#pragma unroll
  for (int off = 1; off < 64; off <<= 1) s += __shfl_xor(s, off, 64);
  if (lane == 0) out[b * 40 + o] = s + L3b[o];
}

// ---------------------------------------------------------------------------
extern "C" void kernel_launch(void* const* d_in, const int* in_sizes, int n_in,
                              void* d_out, int out_size, void* d_ws, size_t ws_size,
                              hipStream_t stream) {
  const float* x = (const float*)d_in[0];
  const float* W1 = (const float*)d_in[1];
  const float* W2 = (const float*)d_in[2];
  const float* W3 = (const float*)d_in[3];
  const float* W4 = (const float*)d_in[4];
  const float* W5 = (const float*)d_in[5];
  const float* g1 = (const float*)d_in[6];  const float* b1 = (const float*)d_in[7];
  const float* g2 = (const float*)d_in[8];  const float* b2 = (const float*)d_in[9];
  const float* g3 = (const float*)d_in[10]; const float* b3 = (const float*)d_in[11];
  const float* g4 = (const float*)d_in[12]; const float* b4 = (const float*)d_in[13];
  const float* g5 = (const float*)d_in[14]; const float* b5 = (const float*)d_in[15];
  const float* g6 = (const float*)d_in[16]; const float* b6 = (const float*)d_in[17];
  const float* g7 = (const float*)d_in[18]; const float* b7 = (const float*)d_in[19];
  const float* L1W = (const float*)d_in[20];
  const float* L2W = (const float*)d_in[21];
  const float* L2b = (const float*)d_in[22];
  const float* L3W = (const float*)d_in[23];
  const float* L3b = (const float*)d_in[24];

  char* w = (char*)d_ws;
  int* idxb = (int*)(w + WS_IDX);
  float* xx = (float*)(w + WS_XX);
  _Float16* y16 = (_Float16*)(w + WS_Y16);
  _Float16* xcat16 = (_Float16*)(w + WS_XCAT16);
  _Float16* w16 = (_Float16*)(w + WS_W16);
  float* pmax = (float*)(w + WS_PMAX);
  float* psum = (float*)(w + WS_PSUM);
  float* fmax = (float*)(w + WS_FMAX);
  float* fsum = (float*)(w + WS_FSUM);
  float* a1 = (float*)(w + WS_A1);
  float* a2 = (float*)(w + WS_A2);

  prep_kernel<<<2288, 256, 0, stream>>>(W2, W3, W4, W5, x, w16, xx);
  knn_kernel<<<4096, 256, 0, stream>>>(x, xx, idxb);
  y1_kernel<<<4096, 256, 0, stream>>>(x, W1, y16);
  gmax_kernel<64, 0><<<4096, 256, 0, stream>>>(y16, idxb, g1, b1, xcat16);
  gemm_mfma<64, 64, 0><<<dim3(128, 1), 256, 0, stream>>>(w16, xcat16, y16);
  gmax_kernel<64, 64><<<4096, 256, 0, stream>>>(y16, idxb, g2, b2, xcat16);
  gemm_mfma<64, 128, 64><<<dim3(128, 1), 256, 0, stream>>>(w16 + 4096, xcat16, y16);
  gmax_kernel<128, 128><<<8192, 256, 0, stream>>>(y16, idxb, g3, b3, xcat16);
  gemm_mfma<128, 256, 128><<<dim3(128, 2), 256, 0, stream>>>(w16 + 12288, xcat16, y16);
  gmax_kernel<256, 256><<<16384, 256, 0, stream>>>(y16, idxb, g4, b4, xcat16);
  gemm5_kernel<<<dim3(128, 8), 256, 0, stream>>>(w16 + 45056, xcat16, g5, b5, pmax, psum);
  reduce5_kernel<<<32, 256, 0, stream>>>(pmax, psum, fmax, fsum);
  l1_kernel<<<1024, 256, 0, stream>>>(fmax, fsum, L1W, g6, b6, a1);
  l2_kernel<<<512, 256, 0, stream>>>(a1, L2W, L2b, g7, b7, a2);
  l3_kernel<<<80, 256, 0, stream>>>(a2, L3W, L3b, (float*)d_out);
}

// Round 4
// 254.095 us; speedup vs baseline: 2.0381x; 1.1926x over previous
//
#include <hip/hip_runtime.h>
#include <math.h>

// ---------------------------------------------------------------------------
// DGCNN-style network, B=8, N=2048, K=20, eval-mode BN.
// Round 4: knn spill fix (__launch_bounds__(256,1)) + 16-bit prefix bisection
// with exact tail extraction; y1+gmax1 fused into edge1 (on-the-fly neighbor
// features); gmax vectorized f16x4. GEMMs unchanged (fp16 MFMA).
// Trick (verified r1-r3): max_k lrelu(bn(h)) == lrelu(bn(max_k h)) for bn
// scale>=0, min_k when scale<0 -> gather reduces max AND min of pre-BN y.
// ---------------------------------------------------------------------------

#define WS_IDX      0            // int[16384*20]            1,310,720 B
#define WS_XX       1310720      // float[16384]             65,536 B
#define WS_Y16      1376256      // half[16384*256]          8,388,608 B
#define WS_XCAT16   9764864      // half[16384*512]          16,777,216 B
#define WS_W16      26542080     // half[569344]             1,138,688 B
#define WS_PMAX     27680768     // float[128*1024]          524,288 B
#define WS_PSUM     28205056     // float[128*1024]          524,288 B
#define WS_FMAX     28729344     // float[8*1024]            32,768 B
#define WS_FSUM     28762112     // float[8*1024]            32,768 B
#define WS_A1       28794880     // float[8*512]             16,384 B
#define WS_A2       28811264     // float[8*256]             8,192 B
// total ~28.8 MB

typedef _Float16 f16x8 __attribute__((ext_vector_type(8)));
typedef _Float16 f16x4 __attribute__((ext_vector_type(4)));
typedef float f32x4 __attribute__((ext_vector_type(4)));

__device__ __forceinline__ float lrelu(float v) { return (v >= 0.f) ? v : 0.2f * v; }

// -------- prep: convert W2..W5 -> fp16 block + per-point sum-of-squares -----
// w16 layout (elements): W2@0 (4096), W3@4096 (8192), W4@12288 (32768),
// W5@45056 (524288). Tail threads compute xx[16384].
__global__ __launch_bounds__(256) void prep_kernel(
    const float* __restrict__ W2, const float* __restrict__ W3,
    const float* __restrict__ W4, const float* __restrict__ W5,
    const float* __restrict__ x, _Float16* __restrict__ w16,
    float* __restrict__ xx) {
  int i = blockIdx.x * 256 + threadIdx.x;
  if (i < 4096) w16[i] = (_Float16)W2[i];
  else if (i < 12288) w16[i] = (_Float16)W3[i - 4096];
  else if (i < 45056) w16[i] = (_Float16)W4[i - 12288];
  else if (i < 569344) w16[i] = (_Float16)W5[i - 45056];
  else if (i < 585728) {
    int p = i - 569344;
    int b = p >> 11, n = p & 2047;
    const float* xb = x + b * 6144;
    float a0 = xb[n], a1 = xb[2048 + n], a2 = xb[4096 + n];
    xx[p] = a0 * a0 + a1 * a1 + a2 * a2;
  }
}

// ------------------------------ KNN ----------------------------------------
// One wave per query row; 32 candidates/lane as sortable-u32 keys of fp32
// neg-distance (keys in [0, 0x80000000]). 16-iteration bisection over the
// 16-bit PREFIX finds T = lo<<16 with count(key>=T)>=20 > count(key>=T+64Ki).
// Sure members (key >= T+64Ki) emitted via ballot prefix; the few boundary
// candidates (prefix == lo) resolved exactly by (key desc, index asc) using
// recomputed u64 packs -- matches jax.lax.top_k stable tie-break. Output
// ORDER is free (idx only feeds max/min reduces).
// __launch_bounds__(256,1): key[32] must stay in VGPRs (r3: 36-VGPR cap
// spilled it to scratch -> VALUBusy 48%).
__global__ __launch_bounds__(256, 1) void knn_kernel(const float* __restrict__ x,
                                                     const float* __restrict__ xx,
                                                     int* __restrict__ idxo) {
  int row = blockIdx.x * 4 + (threadIdx.x >> 6);
  int lane = threadIdx.x & 63;
  int b = row >> 11, n = row & 2047;
  const float* xb = x + b * 6144;
  const float* xxb = xx + b * 2048;
  float q0 = xb[n], q1 = xb[2048 + n], q2 = xb[4096 + n];
  float xxq = xxb[n];
  unsigned key[32];
#pragma unroll
  for (int j = 0; j < 32; ++j) {
    int m = j * 64 + lane;
    float inner = q0 * xb[m] + q1 * xb[2048 + m] + q2 * xb[4096 + m];
    float nd = 2.0f * inner - xxq - xxb[m];
    unsigned bb2 = __float_as_uint(nd);
    key[j] = (bb2 & 0x80000000u) ? ~bb2 : (bb2 | 0x80000000u);
  }
  // prefix bisection: invariant f(lo<<16)>=20, f(hi<<16)<20
  unsigned lo = 0u, hi = 0x8001u;
  for (int it = 0; it < 16; ++it) {
    unsigned mid = (lo + hi + 1) >> 1;
    unsigned mv = mid << 16;
    int cnt = 0;
#pragma unroll
    for (int j = 0; j < 32; ++j)
      cnt += __popcll(__ballot(key[j] >= mv));
    if (cnt >= 20) lo = mid; else hi = mid;
  }
  unsigned T = lo << 16;
  unsigned TH = (lo + 1) << 16;
  // emit sure members, positions via ballot prefix
  unsigned long long ltmask = (1ull << lane) - 1ull;
  int outb = row * 20;
  int c1 = 0;
#pragma unroll
  for (int j = 0; j < 32; ++j) {
    unsigned long long msk = __ballot(key[j] >= TH);
    if (key[j] >= TH) idxo[outb + c1 + __popcll(msk & ltmask)] = j * 64 + lane;
    c1 += __popcll(msk);
  }
  // boundary candidates (T <= key < TH): take (20-c1) by key desc, index asc
  int need = 20 - c1;
  unsigned long long prevp = ~0ull;
  for (int r = 0; r < need; ++r) {
    unsigned long long best = 0;
#pragma unroll
    for (int j = 0; j < 32; ++j) {
      int m = j * 64 + lane;
      unsigned long long p =
          (key[j] >= T && key[j] < TH)
              ? ((((unsigned long long)key[j]) << 32) | (unsigned)(2047 - m))
              : 0ull;
      bool ok = (p < prevp) & (p > best);
      best = ok ? p : best;
    }
#pragma unroll
    for (int off = 1; off < 64; off <<= 1) {
      unsigned long long o = __shfl_xor(best, off, 64);
      best = (o > best) ? o : best;
    }
    if (lane == 0) idxo[outb + c1 + r] = 2047 - (int)(best & 0xFFFFFFFFu);
    prevp = best;
  }
}

// ------------- edge1: fused y1 = W1@x (neighbors) + max/min + BN ------------
// One wave per point: 64 channels. 20 neighbor coords staged in LDS
// (all lanes read the same coord per k -> LDS broadcast, conflict-free).
__global__ __launch_bounds__(256) void edge1_kernel(
    const float* __restrict__ x, const int* __restrict__ idx,
    const float* __restrict__ W1, const float* __restrict__ g,
    const float* __restrict__ bb, _Float16* __restrict__ xcat) {
  __shared__ float nb[4][20][3];
  int tid = threadIdx.x;
  int lpt = tid >> 6, lane = tid & 63;
  int pt = blockIdx.x * 4 + lpt;
  int b = pt >> 11;
  if (lane < 20) {
    int m = idx[pt * 20 + lane];
    const float* xb = x + b * 6144;
    nb[lpt][lane][0] = xb[m];
    nb[lpt][lane][1] = xb[2048 + m];
    nb[lpt][lane][2] = xb[4096 + m];
  }
  __syncthreads();
  float w0 = W1[lane * 3 + 0], w1 = W1[lane * 3 + 1], w2 = W1[lane * 3 + 2];
  float mx = -3.4e38f, mn = 3.4e38f;
#pragma unroll
  for (int k = 0; k < 20; ++k) {
    float v = w0 * nb[lpt][k][0] + w1 * nb[lpt][k][1] + w2 * nb[lpt][k][2];
    mx = fmaxf(mx, v);
    mn = fminf(mn, v);
  }
  float s = g[lane] / sqrtf(1.0f + 1e-5f);
  float v = (s >= 0.0f) ? mx : mn;
  xcat[pt * 512 + lane] = (_Float16)lrelu(s * v + bb[lane]);
}

// --------------- gather max/min + BN + lrelu -> fp16 (f16x4) ----------------
template <int C, int COFF>
__global__ __launch_bounds__(256) void gmax_kernel(const _Float16* __restrict__ y,
                                                   const int* __restrict__ idx,
                                                   const float* __restrict__ g,
                                                   const float* __restrict__ bb,
                                                   _Float16* __restrict__ xcat) {
  constexpr int TP = C / 4;  // threads per point, 4 channels each
  int e = blockIdx.x * 256 + threadIdx.x;  // 16384*TP threads
  int c4 = e & (TP - 1);
  int pg = e / TP;
  int b = pg >> 11;
  const int* ix = idx + pg * 20;
  int mm[20];
#pragma unroll
  for (int k = 0; k < 20; ++k) mm[k] = ix[k];
  int base = b * 2048 * C + c4 * 4;
  float mx[4], mn[4];
#pragma unroll
  for (int i = 0; i < 4; ++i) { mx[i] = -3.4e38f; mn[i] = 3.4e38f; }
#pragma unroll
  for (int k = 0; k < 20; ++k) {
    f16x4 v = *(const f16x4*)&y[base + mm[k] * C];
#pragma unroll
    for (int i = 0; i < 4; ++i) {
      float f = (float)v[i];
      mx[i] = fmaxf(mx[i], f);
      mn[i] = fminf(mn[i], f);
    }
  }
  float4 gv = *(const float4*)&g[c4 * 4];
  float4 bv = *(const float4*)&bb[c4 * 4];
  float gs[4] = {gv.x, gv.y, gv.z, gv.w};
  float bs[4] = {bv.x, bv.y, bv.z, bv.w};
  float inv = 1.0f / sqrtf(1.0f + 1e-5f);
  f16x4 outv;
#pragma unroll
  for (int i = 0; i < 4; ++i) {
    float s = gs[i] * inv;
    float v = (s >= 0.0f) ? mx[i] : mn[i];
    outv[i] = (_Float16)lrelu(s * v + bs[i]);
  }
  *(f16x4*)&xcat[pg * 512 + COFF + c4 * 4] = outv;
}

// ------------- fp16 MFMA GEMM: Y16 = Wh @ xcat-slice ------------------------
// BM=128, BN=min(COUT,128), BK=32. 4 waves: BN==128 -> 2x2 (64x64/wave),
// BN==64 -> 4x1 (32x64/wave). Fragment layouts (m89/m120 verified).
template <int CIN, int COUT, int XOFF>
__global__ __launch_bounds__(256) void gemm_mfma(const _Float16* __restrict__ Wh,
                                                 const _Float16* __restrict__ Xc,
                                                 _Float16* __restrict__ Y) {
  constexpr int BN = (COUT < 128) ? COUT : 128;
  constexpr int MT = (BN == 128) ? 4 : 2;
  __shared__ _Float16 Xs[128 * 40];
  __shared__ _Float16 Ws[BN * 40];
  int tid = threadIdx.x;
  int lane = tid & 63, w = tid >> 6;
  int wm = (BN == 128) ? (w & 1) : w;
  int wn = (BN == 128) ? (w >> 1) : 0;
  int col = lane & 15, quad = lane >> 4;
  int pg0 = blockIdx.x * 128;
  int o0 = blockIdx.y * BN;
  int r0 = tid >> 2;
  int c8 = (tid & 3) * 8;
  f32x4 acc[MT][4] = {};
  for (int k0 = 0; k0 < CIN; k0 += 32) {
    f16x8 xa = *(const f16x8*)&Xc[(pg0 + r0) * 512 + XOFF + k0 + c8];
    f16x8 xb2 = *(const f16x8*)&Xc[(pg0 + r0 + 64) * 512 + XOFF + k0 + c8];
    f16x8 wa = *(const f16x8*)&Wh[(o0 + r0) * CIN + k0 + c8];
    f16x8 wb;
    if (BN == 128) wb = *(const f16x8*)&Wh[(o0 + r0 + 64) * CIN + k0 + c8];
    __syncthreads();
    *(f16x8*)&Xs[r0 * 40 + c8] = xa;
    *(f16x8*)&Xs[(r0 + 64) * 40 + c8] = xb2;
    *(f16x8*)&Ws[r0 * 40 + c8] = wa;
    if (BN == 128) *(f16x8*)&Ws[(r0 + 64) * 40 + c8] = wb;
    __syncthreads();
    f16x8 af[MT], bf[4];
#pragma unroll
    for (int t = 0; t < MT; ++t)
      af[t] = *(const f16x8*)&Xs[(wm * (MT * 16) + t * 16 + col) * 40 + quad * 8];
#pragma unroll
    for (int t = 0; t < 4; ++t)
      bf[t] = *(const f16x8*)&Ws[(wn * 64 + t * 16 + col) * 40 + quad * 8];
#pragma unroll
    for (int mt = 0; mt < MT; ++mt)
#pragma unroll
      for (int nt = 0; nt < 4; ++nt)
        acc[mt][nt] = __builtin_amdgcn_mfma_f32_16x16x32_f16(af[mt], bf[nt],
                                                             acc[mt][nt], 0, 0, 0);
  }
#pragma unroll
  for (int mt = 0; mt < MT; ++mt)
#pragma unroll
    for (int nt = 0; nt < 4; ++nt)
#pragma unroll
      for (int r = 0; r < 4; ++r) {
        int p = pg0 + wm * (MT * 16) + mt * 16 + quad * 4 + r;
        int ch = o0 + wn * 64 + nt * 16 + col;
        Y[p * COUT + ch] = (_Float16)acc[mt][nt][r];
      }
}

// ------------- gemm5: h = lrelu(bn(W5h @ xcat16)) via fp16 MFMA -------------
__global__ __launch_bounds__(256) void gemm5_kernel(
    const _Float16* __restrict__ Wh, const _Float16* __restrict__ Xc,
    const float* __restrict__ g5, const float* __restrict__ b5,
    float* __restrict__ pmax, float* __restrict__ psum) {
  __shared__ _Float16 Xs[128 * 40];
  __shared__ _Float16 Ws[128 * 40];
  __shared__ float pm[256], ps[256];
  int tid = threadIdx.x;
  int lane = tid & 63, w = tid >> 6;
  int wm = w & 1, wn = w >> 1;
  int col = lane & 15, quad = lane >> 4;
  int pg0 = blockIdx.x * 128;
  int o0 = blockIdx.y * 128;
  int r0 = tid >> 2;
  int c8 = (tid & 3) * 8;

  f32x4 acc[4][4] = {};
  for (int k0 = 0; k0 < 512; k0 += 32) {
    f16x8 xa = *(const f16x8*)&Xc[(pg0 + r0) * 512 + k0 + c8];
    f16x8 xb = *(const f16x8*)&Xc[(pg0 + r0 + 64) * 512 + k0 + c8];
    f16x8 wa = *(const f16x8*)&Wh[(o0 + r0) * 512 + k0 + c8];
    f16x8 wb = *(const f16x8*)&Wh[(o0 + r0 + 64) * 512 + k0 + c8];
    __syncthreads();
    *(f16x8*)&Xs[r0 * 40 + c8] = xa;
    *(f16x8*)&Xs[(r0 + 64) * 40 + c8] = xb;
    *(f16x8*)&Ws[r0 * 40 + c8] = wa;
    *(f16x8*)&Ws[(r0 + 64) * 40 + c8] = wb;
    __syncthreads();
    f16x8 af[4], bf[4];
#pragma unroll
    for (int t = 0; t < 4; ++t) {
      af[t] = *(const f16x8*)&Xs[(wm * 64 + t * 16 + col) * 40 + quad * 8];
      bf[t] = *(const f16x8*)&Ws[(wn * 64 + t * 16 + col) * 40 + quad * 8];
    }
#pragma unroll
    for (int mt = 0; mt < 4; ++mt)
#pragma unroll
      for (int nt = 0; nt < 4; ++nt)
        acc[mt][nt] = __builtin_amdgcn_mfma_f32_16x16x32_f16(af[mt], bf[nt],
                                                             acc[mt][nt], 0, 0, 0);
  }
  float inv = 1.0f / sqrtf(1.0f + 1e-5f);
#pragma unroll
  for (int nt = 0; nt < 4; ++nt) {
    int o = o0 + wn * 64 + nt * 16 + col;
    float sc = g5[o] * inv, bi = b5[o];
    float mx = -3.4e38f, sm = 0.f;
#pragma unroll
    for (int mt = 0; mt < 4; ++mt)
#pragma unroll
      for (int r = 0; r < 4; ++r) {
        float v = lrelu(acc[mt][nt][r] * sc + bi);
        mx = fmaxf(mx, v);
        sm += v;
      }
    mx = fmaxf(mx, __shfl_xor(mx, 16, 64));
    sm += __shfl_xor(sm, 16, 64);
    mx = fmaxf(mx, __shfl_xor(mx, 32, 64));
    sm += __shfl_xor(sm, 32, 64);
    if (quad == 0) {
      pm[wm * 128 + wn * 64 + nt * 16 + col] = mx;
      ps[wm * 128 + wn * 64 + nt * 16 + col] = sm;
    }
  }
  __syncthreads();
  if (tid < 128) {
    float m = fmaxf(pm[tid], pm[128 + tid]);
    float s = ps[tid] + ps[128 + tid];
    pmax[blockIdx.x * 1024 + o0 + tid] = m;
    psum[blockIdx.x * 1024 + o0 + tid] = s;
  }
}

// fold 16 m-block partials per (batch, channel)
__global__ __launch_bounds__(256) void reduce5_kernel(const float* __restrict__ pmax,
                                                      const float* __restrict__ psum,
                                                      float* __restrict__ fmax,
                                                      float* __restrict__ fsum) {
  int t = blockIdx.x * 256 + threadIdx.x;  // 8192
  int b = t >> 10, o = t & 1023;
  float m = -3.4e38f, s = 0.f;
#pragma unroll
  for (int i = 0; i < 16; ++i) {
    m = fmaxf(m, pmax[(b * 16 + i) * 1024 + o]);
    s += psum[(b * 16 + i) * 1024 + o];
  }
  fmax[t] = m;
  fsum[t] = s;
}

// ------------------------------ MLP head ------------------------------------
__global__ __launch_bounds__(256) void l1_kernel(const float* __restrict__ fmax,
                                                 const float* __restrict__ fsum,
                                                 const float* __restrict__ L1W,
                                                 const float* __restrict__ g6,
                                                 const float* __restrict__ b6,
                                                 float* __restrict__ a1) {
  int gw = (blockIdx.x * 256 + threadIdx.x) >> 6;  // 4096 waves
  int lane = threadIdx.x & 63;
  int b = gw >> 9, o = gw & 511;
  float s = 0.f;
#pragma unroll
  for (int i = 0; i < 32; ++i) {
    int j = lane + i * 64;
    float fj = (j < 1024) ? fmax[b * 1024 + j]
                          : fsum[b * 1024 + j - 1024] * (1.0f / 2048.0f);
    s += fj * L1W[o * 2048 + j];
  }
#pragma unroll
  for (int off = 1; off < 64; off <<= 1) s += __shfl_xor(s, off, 64);
  if (lane == 0) {
    float scv = g6[o] / sqrtf(1.0f + 1e-5f);
    a1[b * 512 + o] = lrelu(s * scv + b6[o]);
  }
}

__global__ __launch_bounds__(256) void l2_kernel(const float* __restrict__ a1,
                                                 const float* __restrict__ L2W,
                                                 const float* __restrict__ L2b,
                                                 const float* __restrict__ g7,
                                                 const float* __restrict__ b7,
                                                 float* __restrict__ a2) {
  int gw = (blockIdx.x * 256 + threadIdx.x) >> 6;  // 2048 waves
  int lane = threadIdx.x & 63;
  int b = gw >> 8, o = gw & 255;
  float s = 0.f;
#pragma unroll
  for (int i = 0; i < 8; ++i) {
    int j = lane + i * 64;
    s += a1[b * 512 + j] * L2W[o * 512 + j];
  }
#pragma unroll
  for (int off = 1; off < 64; off <<= 1) s += __shfl_xor(s, off, 64);
  if (lane == 0) {
    float v = s + L2b[o];
    float scv = g7[o] / sqrtf(1.0f + 1e-5f);
    a2[b * 256 + o] = lrelu(v * scv + b7[o]);
  }
}

__global__ __launch_bounds__(256) void l3_kernel(const float* __restrict__ a2,
                                                 const float* __restrict__ L3W,
                                                 const float* __restrict__ L3b,
                                                 float* __restrict__ out) {
  int gw = (blockIdx.x * 256 + threadIdx.x) >> 6;  // 320 waves
  int lane = threadIdx.x & 63;
  int b = gw / 40, o = gw % 40;
  float s = 0.f;
#pragma unroll
  for (int i = 0; i < 4; ++i) {
    int j = lane + i * 64;
    s += a2[b * 256 + j] * L3W[o * 256 + j];
  }
#pragma unroll
  for (int off = 1; off < 64; off <<= 1) s += __shfl_xor(s, off, 64);
  if (lane == 0) out[b * 40 + o] = s + L3b[o];
}

// ---------------------------------------------------------------------------
extern "C" void kernel_launch(void* const* d_in, const int* in_sizes, int n_in,
                              void* d_out, int out_size, void* d_ws, size_t ws_size,
                              hipStream_t stream) {
  const float* x = (const float*)d_in[0];
  const float* W1 = (const float*)d_in[1];
  const float* W2 = (const float*)d_in[2];
  const float* W3 = (const float*)d_in[3];
  const float* W4 = (const float*)d_in[4];
  const float* W5 = (const float*)d_in[5];
  const float* g1 = (const float*)d_in[6];  const float* b1 = (const float*)d_in[7];
  const float* g2 = (const float*)d_in[8];  const float* b2 = (const float*)d_in[9];
  const float* g3 = (const float*)d_in[10]; const float* b3 = (const float*)d_in[11];
  const float* g4 = (const float*)d_in[12]; const float* b4 = (const float*)d_in[13];
  const float* g5 = (const float*)d_in[14]; const float* b5 = (const float*)d_in[15];
  const float* g6 = (const float*)d_in[16]; const float* b6 = (const float*)d_in[17];
  const float* g7 = (const float*)d_in[18]; const float* b7 = (const float*)d_in[19];
  const float* L1W = (const float*)d_in[20];
  const float* L2W = (const float*)d_in[21];
  const float* L2b = (const float*)d_in[22];
  const float* L3W = (const float*)d_in[23];
  const float* L3b = (const float*)d_in[24];

  char* w = (char*)d_ws;
  int* idxb = (int*)(w + WS_IDX);
  float* xx = (float*)(w + WS_XX);
  _Float16* y16 = (_Float16*)(w + WS_Y16);
  _Float16* xcat16 = (_Float16*)(w + WS_XCAT16);
  _Float16* w16 = (_Float16*)(w + WS_W16);
  float* pmax = (float*)(w + WS_PMAX);
  float* psum = (float*)(w + WS_PSUM);
  float* fmax = (float*)(w + WS_FMAX);
  float* fsum = (float*)(w + WS_FSUM);
  float* a1 = (float*)(w + WS_A1);
  float* a2 = (float*)(w + WS_A2);

  prep_kernel<<<2288, 256, 0, stream>>>(W2, W3, W4, W5, x, w16, xx);
  knn_kernel<<<4096, 256, 0, stream>>>(x, xx, idxb);
  edge1_kernel<<<4096, 256, 0, stream>>>(x, idxb, W1, g1, b1, xcat16);
  gemm_mfma<64, 64, 0><<<dim3(128, 1), 256, 0, stream>>>(w16, xcat16, y16);
  gmax_kernel<64, 64><<<1024, 256, 0, stream>>>(y16, idxb, g2, b2, xcat16);
  gemm_mfma<64, 128, 64><<<dim3(128, 1), 256, 0, stream>>>(w16 + 4096, xcat16, y16);
  gmax_kernel<128, 128><<<2048, 256, 0, stream>>>(y16, idxb, g3, b3, xcat16);
  gemm_mfma<128, 256, 128><<<dim3(128, 2), 256, 0, stream>>>(w16 + 12288, xcat16, y16);
  gmax_kernel<256, 256><<<4096, 256, 0, stream>>>(y16, idxb, g4, b4, xcat16);
  gemm5_kernel<<<dim3(128, 8), 256, 0, stream>>>(w16 + 45056, xcat16, g5, b5, pmax, psum);
  reduce5_kernel<<<32, 256, 0, stream>>>(pmax, psum, fmax, fsum);
  l1_kernel<<<1024, 256, 0, stream>>>(fmax, fsum, L1W, g6, b6, a1);
  l2_kernel<<<512, 256, 0, stream>>>(a1, L2W, L2b, g7, b7, a2);
  l3_kernel<<<80, 256, 0, stream>>>(a2, L3W, L3b, (float*)d_out);
}